// Round 9
// baseline (84.467 us; speedup 1.0000x reference)
//
#include <hip/hip_runtime.h>
#include <float.h>
#include <limits.h>

// NearestCluster: per-batch NN argmin via uniform 8^3 grid (exact).
// coords1 [L1=4096, N=8, C=3] f32 (reference), coords2 [L2=4096, N=8, C=3] f32 (query)
// out int32: [L2*N] argmin idx over L1 per batch, then [L2*N] batch idx.
//
// Numerics: bit-exact vs numpy f32 reference:
//   qq = (q0*q0 + q1*q1) + q2*q2         rr likewise (round each op, no fma)
//   dot = ((q0*r0) + (q1*r1)) + (q2*r2)
//   d2 = (qq + rr) - 2*dot  ==  fma(-2, dot, qq+rr)   (2*dot exact)
// Ties -> lowest ORIGINAL index: candidates carry orig idx; every update and
// merge is lexicographic on (d2, idx) -> within-cell order irrelevant.
// Cell assignment: x*8 is EXACT (pow2 mul), so cell = floor(x*8) is exact ->
// geometric pruning bound holds exactly.
//
// R9 post-mortem: bench-adder arithmetic (stable ~46us fill+gaps) puts my
// kernels at ~36us; grid_nn models at ~6-7us -> bin_kernel ~25-28us. Cause:
// 8 blocks (3% of GPU), 12 stride-96B gathers/thread (64 lines per wave-load),
// cold HBM, divergent scatter. R10: 4-kernel pipeline, bin work spread over
// 128 blocks with all heavy reads coalesced; grid_nn BYTE-IDENTICAL to R9
// (single-variable experiment).
//   K1 cellof:   thread t reads c1[3t..3t+2] (flat layout is contiguous in t),
//                writes cellOf[t] coalesced. No atomics.
//   K2 histscan: 8 blocks; LDS histogram from cellOf (stride-32B int reads),
//                R7-proven wave-0 shfl scan -> cellStart + global cursor.
//   K3 scatter:  coalesced re-read c1+cellOf (L2-hot), atomicAdd cursor,
//                scatter-write pts (x,y,z,idx).
//   K4 grid_nn:  R9 branch-free compacted 3x3x3 walk, unchanged.
//
// Pruning exactness (unchanged): outside the 3^3 neighborhood every point has
// an axis gap > 1/8 => true d2 > lb = 0.015625 (exact). Computed-vs-true d2
// error <= ~3.6e-6; skip fallback only when lb > bd + 4e-6 => pruned points'
// COMPUTED d2 > bd => never argmin nor tie. Empty neighborhood -> bd=FLT_MAX
// -> full rescan fallback.
//
// ws layout (688384 B): cellStart[8][520] | cursor[8][512] | cellOf[32768] |
//                       pts[8][4096] float4. All offsets 16B-aligned.
// Fallback to the verified R5 LDS brute-force kernel if ws too small.

constexpr int kL1 = 4096, kL2 = 4096, kN = 8;
constexpr int kCS = 520;
constexpr size_t kOffCursor = 8ull * kCS * 4;                 // 16640
constexpr size_t kOffCellOf = kOffCursor + 8ull * 512 * 4;    // 33024
constexpr size_t kOffPts = kOffCellOf + 32768ull * 4;         // 164096
constexpr size_t kWsBytes = kOffPts + 8ull * kL1 * 16;        // 688384

__device__ __forceinline__ float rr_exact(float x, float y, float z) {
  return __fadd_rn(__fadd_rn(__fmul_rn(x, x), __fmul_rn(y, y)), __fmul_rn(z, z));
}

__device__ __forceinline__ int cell_of(float x, float y, float z) {
  const int cx = min(7, max(0, (int)(x * 8.0f)));
  const int cy = min(7, max(0, (int)(y * 8.0f)));
  const int cz = min(7, max(0, (int)(z * 8.0f)));
  return (cz * 8 + cy) * 8 + cx;
}

// ---- K1: per-point cell id, fully coalesced (flat index t = j*8+n) ----
__global__ __launch_bounds__(256)
void cellof_kernel(const float* __restrict__ c1, int* __restrict__ cellOf) {
  const int t = blockIdx.x * 256 + threadIdx.x;   // 0..32767
  const float x = c1[3 * t], y = c1[3 * t + 1], z = c1[3 * t + 2];
  cellOf[t] = cell_of(x, y, z);
}

// ---- K2: per-batch LDS histogram + scan -> cellStart, cursor ----
__global__ __launch_bounds__(1024)
void histscan_kernel(const int* __restrict__ cellOf, int* __restrict__ cellStart,
                     int* __restrict__ cursor) {
  __shared__ int hist[512];
  const int tid = threadIdx.x;
  const int n = blockIdx.x;
  if (tid < 512) hist[tid] = 0;
  __syncthreads();

#pragma unroll
  for (int k = 0; k < 4; ++k) {
    const int j = k * 1024 + tid;
    atomicAdd(&hist[cellOf[j * kN + n]], 1);
  }
  __syncthreads();

  // Exclusive prefix over 512 counts: wave 0, 8 cells/lane + shfl scan (R7-proven).
  if (tid < 64) {
    int loc[8], part = 0;
#pragma unroll
    for (int i = 0; i < 8; ++i) { loc[i] = hist[tid * 8 + i]; part += loc[i]; }
    int inc = part;
#pragma unroll
    for (int off = 1; off < 64; off <<= 1) {
      const int v = __shfl_up(inc, off);
      if (tid >= off) inc += v;
    }
    int base = inc - part;
#pragma unroll
    for (int i = 0; i < 8; ++i) {
      const int c = tid * 8 + i;
      cellStart[n * kCS + c] = base;
      cursor[n * 512 + c] = base;
      base += loc[i];
    }
    if (tid == 0) cellStart[n * kCS + 512] = kL1;
  }
}

// ---- K3: scatter points into cell-ordered pts (coalesced reads) ----
__global__ __launch_bounds__(256)
void scatter_kernel(const float* __restrict__ c1, const int* __restrict__ cellOf,
                    int* __restrict__ cursor, float4* __restrict__ pts) {
  const int t = blockIdx.x * 256 + threadIdx.x;   // 0..32767
  const int n = t & (kN - 1);
  const int j = t >> 3;
  const float x = c1[3 * t], y = c1[3 * t + 1], z = c1[3 * t + 2];
  const int cell = cellOf[t];
  const int pos = atomicAdd(&cursor[n * 512 + cell], 1);
  pts[n * kL1 + pos] = make_float4(x, y, z, __int_as_float(j));
}

// ------- K4: one wave per query, branch-free compacted 3x3x3 walk (R9) -------
__global__ __launch_bounds__(256, 6)
void grid_nn_kernel(const int* __restrict__ cellStart, const float4* __restrict__ pts,
                    const float* __restrict__ c2, int* __restrict__ out) {
#pragma clang fp contract(off)
  const int n = blockIdx.y;                    // batch (uniform)
  const int wave = threadIdx.x >> 6;
  const int lane = threadIdx.x & 63;
  const int qj = blockIdx.x * 4 + wave;        // query index within batch

  const float* p = c2 + (qj * kN + n) * 3;     // same addr all lanes: broadcast
  const float qx = p[0], qy = p[1], qz = p[2];
  const float qq = rr_exact(qx, qy, qz);
  const int cx = min(7, max(0, (int)(qx * 8.0f)));
  const int cy = min(7, max(0, (int)(qy * 8.0f)));
  const int cz = min(7, max(0, (int)(qz * 8.0f)));
  const int xlo = max(0, cx - 1), xhi = min(7, cx + 1);

  const int* __restrict__ cs = cellStart + n * kCS;
  const float4* __restrict__ P = pts + n * kL1;

  // 9 (z,y) sections, branch-free: 18 independent cs loads all in flight.
  int S[9], Lk[9], pre[10];
#pragma unroll
  for (int k = 0; k < 9; ++k) {
    const int dz = k / 3 - 1, dy = k % 3 - 1;
    const int z = cz + dz, y = cy + dy;
    const bool valid = ((unsigned)z <= 7u) && ((unsigned)y <= 7u);
    const int zc = min(7, max(0, z)), yc = min(7, max(0, y));
    const int row = (zc * 8 + yc) * 8;
    const int s = cs[row + xlo];
    const int e = cs[row + xhi + 1];
    S[k] = s;
    Lk[k] = valid ? (e - s) : 0;
  }
  pre[0] = 0;
#pragma unroll
  for (int k = 0; k < 9; ++k) pre[k + 1] = pre[k] + Lk[k];
  const int T = pre[9];                        // wave-uniform total candidates

  float bd = FLT_MAX;
  int bi = INT_MAX;

  for (int base = 0; base < T; base += 256) {  // 1 trip typ. (T ~ 216)
    int g[4], a[4];
#pragma unroll
    for (int u = 0; u < 4; ++u) {
      g[u] = base + lane + u * 64;
      int ad = 0;                              // g>=T decodes to 0 (in-bounds)
#pragma unroll
      for (int k = 0; k < 9; ++k) {
        const bool in = (g[u] >= pre[k]) && (g[u] < pre[k + 1]);
        ad = in ? (S[k] + (g[u] - pre[k])) : ad;
      }
      a[u] = ad;
    }
    float4 rp[4];
#pragma unroll
    for (int u = 0; u < 4; ++u) rp[u] = P[a[u]];   // 4 independent loads
#pragma unroll
    for (int u = 0; u < 4; ++u) {
      const int id = __float_as_int(rp[u].w);
      const float rr = rr_exact(rp[u].x, rp[u].y, rp[u].z);
      const float dot = __fadd_rn(
          __fadd_rn(__fmul_rn(qx, rp[u].x), __fmul_rn(qy, rp[u].y)),
          __fmul_rn(qz, rp[u].z));
      const float d2 = __fmaf_rn(-2.0f, dot, __fadd_rn(qq, rr));
      if (g[u] < T && (d2 < bd || (d2 == bd && id < bi))) { bd = d2; bi = id; }
    }
  }

  // Merge across the wave (lexicographic on (d2, idx)).
#pragma unroll
  for (int m = 1; m <= 32; m <<= 1) {
    const float od = __shfl_xor(bd, m);
    const int oi = __shfl_xor(bi, m);
    if (od < bd || (od == bd && oi < bi)) { bd = od; bi = oi; }
  }

  // Fallback (wave-uniform, astronomically rare): rescan all points exactly.
  if (!(0.015625f > __fadd_rn(bd, 4e-6f))) {
    for (int pp = lane; pp < kL1; pp += 64) {
      const float4 rp = P[pp];
      const int id = __float_as_int(rp.w);
      const float rr = rr_exact(rp.x, rp.y, rp.z);
      const float dot = __fadd_rn(
          __fadd_rn(__fmul_rn(qx, rp.x), __fmul_rn(qy, rp.y)),
          __fmul_rn(qz, rp.z));
      const float d2 = __fmaf_rn(-2.0f, dot, __fadd_rn(qq, rr));
      if (d2 < bd || (d2 == bd && id < bi)) { bd = d2; bi = id; }
    }
#pragma unroll
    for (int m = 1; m <= 32; m <<= 1) {
      const float od = __shfl_xor(bd, m);
      const int oi = __shfl_xor(bi, m);
      if (od < bd || (od == bd && oi < bi)) { bd = od; bi = oi; }
    }
  }

  if (lane == 0) {
    out[qj * kN + n] = bi;
    out[kL2 * kN + qj * kN + n] = n;
  }
}

// ---------------- Fallback (verified R5/R6 brute force, LDS) ----------------
constexpr int kQPerBlock = 16;
constexpr int kQ = 4;
constexpr int kChunk = 1024;

__global__ __launch_bounds__(256, 4)
void nearest_kernel_lds(const float* __restrict__ c1, const float* __restrict__ c2,
                        int* __restrict__ out) {
#pragma clang fp contract(off)
  __shared__ float sRx[kChunk], sRy[kChunk], sRz[kChunk], sRr[kChunk];
  const int tid = threadIdx.x;
  const int n = blockIdx.y;
  const int wave = tid >> 6;
  const int lane = tid & 63;
  const int q0 = blockIdx.x * kQPerBlock + wave * kQ;

  float qxs[kQ], qys[kQ], qzs[kQ], qqs[kQ];
#pragma unroll
  for (int i = 0; i < kQ; ++i) {
    const float* p = c2 + ((q0 + i) * kN + n) * 3;
    qxs[i] = p[0]; qys[i] = p[1]; qzs[i] = p[2];
    qqs[i] = rr_exact(qxs[i], qys[i], qzs[i]);
  }
  float bd[kQ]; int bt[kQ];
#pragma unroll
  for (int i = 0; i < kQ; ++i) { bd[i] = FLT_MAX; bt[i] = 0; }

  for (int chunk = 0; chunk < kL1 / kChunk; ++chunk) {
    __syncthreads();
    {
      const int jb = chunk * kChunk + tid * 4;
      float x[4], y[4], z[4], w4[4];
#pragma unroll
      for (int k = 0; k < 4; ++k) {
        const float* p = c1 + ((jb + k) * kN + n) * 3;
        x[k] = p[0]; y[k] = p[1]; z[k] = p[2];
        w4[k] = rr_exact(x[k], y[k], z[k]);
      }
      *reinterpret_cast<float4*>(&sRx[tid * 4]) = make_float4(x[0], x[1], x[2], x[3]);
      *reinterpret_cast<float4*>(&sRy[tid * 4]) = make_float4(y[0], y[1], y[2], y[3]);
      *reinterpret_cast<float4*>(&sRz[tid * 4]) = make_float4(z[0], z[1], z[2], z[3]);
      *reinterpret_cast<float4*>(&sRr[tid * 4]) = make_float4(w4[0], w4[1], w4[2], w4[3]);
    }
    __syncthreads();
#pragma unroll
    for (int t = 0; t < kChunk / 256; ++t) {
      const int tg = chunk * (kChunk / 256) + t;
      const int base = t * 256 + lane * 4;
      const float4 x4 = *reinterpret_cast<const float4*>(&sRx[base]);
      const float4 y4 = *reinterpret_cast<const float4*>(&sRy[base]);
      const float4 z4 = *reinterpret_cast<const float4*>(&sRz[base]);
      const float4 r4 = *reinterpret_cast<const float4*>(&sRr[base]);
      const float xs[4] = {x4.x, x4.y, x4.z, x4.w};
      const float ys[4] = {y4.x, y4.y, y4.z, y4.w};
      const float zs[4] = {z4.x, z4.y, z4.z, z4.w};
      const float rs[4] = {r4.x, r4.y, r4.z, r4.w};
#pragma unroll
      for (int i = 0; i < kQ; ++i) {
        float d[4];
#pragma unroll
        for (int k = 0; k < 4; ++k) {
          const float dot = __fadd_rn(
              __fadd_rn(__fmul_rn(qxs[i], xs[k]), __fmul_rn(qys[i], ys[k])),
              __fmul_rn(qzs[i], zs[k]));
          d[k] = __fmaf_rn(-2.0f, dot, __fadd_rn(qqs[i], rs[k]));
        }
        const float old = bd[i];
        float m = fminf(fminf(d[0], d[1]), old);
        m = fminf(fminf(d[2], d[3]), m);
        bd[i] = m;
        if (m < old) bt[i] = tg;
      }
    }
  }
  int sel[kQ];
#pragma unroll
  for (int i = 0; i < kQ; ++i) sel[i] = bt[i] * 64 + lane;
#pragma unroll
  for (int m = 1; m <= 32; m <<= 1) {
#pragma unroll
    for (int i = 0; i < kQ; ++i) {
      const float od = __shfl_xor(bd[i], m);
      const int os = __shfl_xor(sel[i], m);
      if (od < bd[i] || (od == bd[i] && os < sel[i])) { bd[i] = od; sel[i] = os; }
    }
  }
#pragma unroll
  for (int i = 0; i < kQ; ++i) {
    if (lane == i) {
      const int j0 = sel[i] * 4;
      float best = FLT_MAX; int kk = 0;
#pragma unroll
      for (int k = 0; k < 4; ++k) {
        const float* p = c1 + ((j0 + k) * kN + n) * 3;
        const float r0 = p[0], r1 = p[1], r2 = p[2];
        const float rr = rr_exact(r0, r1, r2);
        const float dot = __fadd_rn(
            __fadd_rn(__fmul_rn(qxs[i], r0), __fmul_rn(qys[i], r1)),
            __fmul_rn(qzs[i], r2));
        const float dc = __fmaf_rn(-2.0f, dot, __fadd_rn(qqs[i], rr));
        if (dc < best) { best = dc; kk = k; }
      }
      out[(q0 + i) * kN + n] = j0 + kk;
      out[kL2 * kN + (q0 + i) * kN + n] = n;
    }
  }
}

extern "C" void kernel_launch(void* const* d_in, const int* in_sizes, int n_in,
                              void* d_out, int out_size, void* d_ws, size_t ws_size,
                              hipStream_t stream) {
  const float* c1 = (const float*)d_in[0];
  const float* c2 = (const float*)d_in[1];
  int* out = (int*)d_out;
  if (d_ws != nullptr && ws_size >= kWsBytes) {
    int* cellStart = (int*)d_ws;
    int* cursor = (int*)((char*)d_ws + kOffCursor);
    int* cellOf = (int*)((char*)d_ws + kOffCellOf);
    float4* pts = (float4*)((char*)d_ws + kOffPts);
    cellof_kernel<<<dim3(kL1 * kN / 256), dim3(256), 0, stream>>>(c1, cellOf);
    histscan_kernel<<<dim3(kN), dim3(1024), 0, stream>>>(cellOf, cellStart, cursor);
    scatter_kernel<<<dim3(kL1 * kN / 256), dim3(256), 0, stream>>>(
        c1, cellOf, cursor, pts);
    grid_nn_kernel<<<dim3(kL2 / 4, kN), dim3(256), 0, stream>>>(
        cellStart, pts, c2, out);
  } else {
    dim3 grid(kL2 / kQPerBlock, kN);
    nearest_kernel_lds<<<grid, dim3(256), 0, stream>>>(c1, c2, out);
  }
}